// Round 4
// baseline (261.024 us; speedup 1.0000x reference)
//
#include <hip/hip_runtime.h>
#include <hip/hip_bf16.h>
#include <cstdint>

typedef float f32x4 __attribute__((ext_vector_type(4)));
typedef __bf16 bf16x8 __attribute__((ext_vector_type(8)));
typedef __bf16 bf16x4 __attribute__((ext_vector_type(4)));
typedef __bf16 bf16x2 __attribute__((ext_vector_type(2)));
typedef short short4v __attribute__((ext_vector_type(4)));

#define MFMA_K32(A, B, C) __builtin_amdgcn_mfma_f32_16x16x32_bf16((A), (B), (C), 0, 0, 0)

// 16x16x16 bf16 MFMA: device has one of these (R3 device pass compiled clean);
// the final #else only feeds the HOST semantic pass, which never executes it.
#if __has_builtin(__builtin_amdgcn_mfma_f32_16x16x16bf16_1k)
#define MFMA_K16(A, B, C) __builtin_amdgcn_mfma_f32_16x16x16bf16_1k((A), (B), (C), 0, 0, 0)
#elif __has_builtin(__builtin_amdgcn_mfma_f32_16x16x16_bf16)
static __device__ __forceinline__ f32x4 mfma_k16_alt(short4v a, short4v b, f32x4 c) {
    return __builtin_amdgcn_mfma_f32_16x16x16_bf16(*(bf16x4*)&a, *(bf16x4*)&b, c, 0, 0, 0);
}
#define MFMA_K16(A, B, C) mfma_k16_alt((A), (B), (C))
#else
#define MFMA_K16(A, B, C) (C)  // host-pass placeholder only
#endif

#if __has_builtin(__builtin_amdgcn_exp2f)
#define EXP2(x) __builtin_amdgcn_exp2f(x)
#else
#define EXP2(x) exp2f(x)
#endif

// round-to-nearest-even f32 -> bf16 bits
static __device__ __forceinline__ uint16_t f2b(float f) {
    uint32_t u = __float_as_uint(f);
    uint32_t r = (u + 0x7fffu + ((u >> 16) & 1u)) >> 16;
    return (uint16_t)r;
}

// pack two f32 -> bf16x2 dword (low = a, high = b), RNE
static __device__ __forceinline__ uint32_t packbf(float a, float b) {
#if __has_builtin(__builtin_amdgcn_cvt_pk_bf16_f32)
    bf16x2 v = __builtin_amdgcn_cvt_pk_bf16_f32(a, b);
    return *(uint32_t*)&v;
#else
    uint32_t ua = __float_as_uint(a);
    ua += 0x7fffu + ((ua >> 16) & 1u);
    uint32_t ub = __float_as_uint(b);
    ub += 0x7fffu + ((ub >> 16) & 1u);
    return __builtin_amdgcn_perm(ub, ua, 0x07060302);
#endif
}

// ---------------- kernel 0: weights f32->bf16 + PE table -----------------
// blocks 0..1023: weight convert; 1024..1087: pet[cc][pos] (256 x 64 f32)
__global__ __launch_bounds__(256) void wconv_pe(const float* __restrict__ wq,
                                                const float* __restrict__ wk,
                                                const float* __restrict__ wv,
                                                const float* __restrict__ wo,
                                                uint16_t* __restrict__ dst,
                                                float* __restrict__ pet) {
    int bid = blockIdx.x, t = threadIdx.x;
    if (bid < 1024) {
        int idx = bid * 256 + t;
        int which = idx >> 16, off = idx & 65535;
        const float* s = (which == 0) ? wq : (which == 1) ? wk : (which == 2) ? wv : wo;
        dst[idx] = f2b(s[off]);
    } else {
        int idx = (bid - 1024) * 256 + t;   // 0..16383
        int cc = idx >> 6, p = idx & 63;
        int i = (cc & 127) >> 1;
        float dt = __expf((float)(2 * i) * -0.07195578415606394f);  // -(ln 1e4)/128
        float sv, cv;
        __sincosf((float)p * dt, &sv, &cv);
        pet[idx] = (cc & 1) ? cv : sv;
    }
}

// ---------------- kernel 1: tok = (x + pe) transposed, LDS-tiled ----------
// grid 512 = 2 b x 4 c-tiles x 64 n-tiles; tile 64c x 64n
__global__ __launch_bounds__(256) void peadd(const float* __restrict__ x,
                                             const float* __restrict__ pet,
                                             uint16_t* __restrict__ tok) {
    __shared__ uint16_t T[64][65];
    int t = threadIdx.x, bid = blockIdx.x;
    int nt = bid & 63, ct = (bid >> 6) & 3, bb = bid >> 8;
    int n0 = nt << 6, c0 = ct << 6;
    int nl = t & 63, cq = t >> 6;
    int n = n0 + nl;
    int posh = n0 >> 6;  // uniform within tile
#pragma unroll
    for (int p = 0; p < 16; ++p) {
        int cl = cq * 16 + p;
        int cc = c0 + cl;
        float pe = pet[cc * 64 + ((cc & 128) ? posh : nl)];
        T[cl][nl] = f2b(x[((size_t)(bb * 256 + cc) << 12) + n] + pe);
    }
    __syncthreads();
#pragma unroll
    for (int p = 0; p < 16; ++p) {
        int tl = cq * 16 + p;
        tok[(((size_t)(bb << 12) | (n0 + tl)) << 8) + c0 + nl] = T[nl][tl];
    }
}

// ---------------- kernel 2: QKV projection, A-frags resident over 3 mats --
// grid (128 mtiles, 4 otiles), 256 thr = 4 waves
__global__ __launch_bounds__(256) void qkv_gemm(const uint16_t* __restrict__ tok,
                                                const uint16_t* __restrict__ Wall,
                                                const float* __restrict__ bq,
                                                const float* __restrict__ bk,
                                                const float* __restrict__ bv,
                                                uint16_t* __restrict__ qo,
                                                uint16_t* __restrict__ ko,
                                                uint16_t* __restrict__ vo) {
    int tid = threadIdx.x, wv = tid >> 6, lane = tid & 63;
    int c16 = lane & 15, quad = lane >> 4;
    int M0 = blockIdx.x * 64 + wv * 16;
    int O0 = blockIdx.y * 64;
    const uint16_t* arow = tok + (size_t)(M0 + c16) * 256;
    bf16x8 af[8];
#pragma unroll
    for (int kk = 0; kk < 8; ++kk) af[kk] = *(const bf16x8*)(arow + kk * 32 + quad * 8);
    f32x4 zero = {0.f, 0.f, 0.f, 0.f};
    // mats 0,1: Q,K -> [bh,n,d]
#pragma unroll
    for (int mat = 0; mat < 2; ++mat) {
        const uint16_t* W = Wall + (size_t)mat * 65536;
        f32x4 acc[4] = {zero, zero, zero, zero};
#pragma unroll
        for (int kk = 0; kk < 8; ++kk) {
            int k0 = kk * 32 + quad * 8;
#pragma unroll
            for (int nb = 0; nb < 4; ++nb)
                acc[nb] = MFMA_K32(af[kk],
                                   *(const bf16x8*)(W + (size_t)(O0 + nb * 16 + c16) * 256 + k0),
                                   acc[nb]);
        }
        const float* bias = (mat == 0) ? bq : bk;
        float scale = (mat == 0) ? 0.25505654134660127f : 1.0f;  // 1/sqrt(32)*log2(e) in q
        uint16_t* dst = (mat == 0) ? qo : ko;
#pragma unroll
        for (int nb = 0; nb < 4; ++nb) {
            int o = O0 + nb * 16 + c16;
            float bi = bias[o];
            int h = o >> 5, dd = o & 31;
#pragma unroll
            for (int r = 0; r < 4; ++r) {
                int m = M0 + quad * 4 + r;
                int bb = m >> 12, n = m & 4095;
                dst[((size_t)(bb * 8 + h) * 4096 + n) * 32 + dd] =
                    f2b((acc[nb][r] + bi) * scale);
            }
        }
    }
    // mat 2: V, swapped operands -> V^T [bh,d,n]
    {
        const uint16_t* W = Wall + (size_t)2 * 65536;
        f32x4 acc[4] = {zero, zero, zero, zero};
#pragma unroll
        for (int kk = 0; kk < 8; ++kk) {
            int k0 = kk * 32 + quad * 8;
#pragma unroll
            for (int nb = 0; nb < 4; ++nb)
                acc[nb] = MFMA_K32(*(const bf16x8*)(W + (size_t)(O0 + nb * 16 + c16) * 256 + k0),
                                   af[kk], acc[nb]);
        }
        int bb = M0 >> 12, n = (M0 + c16) & 4095;
#pragma unroll
        for (int nb = 0; nb < 4; ++nb)
#pragma unroll
            for (int r = 0; r < 4; ++r) {
                int o = O0 + nb * 16 + quad * 4 + r;
                vo[((size_t)(bb * 8 + (o >> 5)) * 32 + (o & 31)) * 4096 + n] =
                    f2b(acc[nb][r] + bv[o]);
            }
    }
}

// ---------------- kernel 3: flash attention, ZERO LDS --------------------
// grid (32 q-tiles of 128, 16 bh), 256 thr = 4 waves; wave owns 32 q rows.
// K/V fragments loaded straight from global in MFMA layout (L1/L2-served);
// PV uses 16x16x16 MFMA so the S^T C-layout IS the A-layout (no transform).
static __device__ __forceinline__ void attn_qblock(const bf16x8 (&kfc)[4],
                                                   const short4v (&vfc)[2][4],
                                                   bf16x8 qf, f32x4& oA, f32x4& oB,
                                                   float& l) {
    f32x4 zero = {0.f, 0.f, 0.f, 0.f};
    f32x4 s[4];
#pragma unroll
    for (int kc = 0; kc < 4; ++kc) s[kc] = MFMA_K32(kfc[kc], qf, zero);
    float rs = 0.f;
#pragma unroll
    for (int kc = 0; kc < 4; ++kc) {
#pragma unroll
        for (int r = 0; r < 4; ++r) {
            s[kc][r] = EXP2(s[kc][r]);
            rs += s[kc][r];
        }
        union { short4v s4; uint32_t u[2]; } pa;
        pa.u[0] = packbf(s[kc][0], s[kc][1]);
        pa.u[1] = packbf(s[kc][2], s[kc][3]);
        oA = MFMA_K16(pa.s4, vfc[0][kc], oA);
        oB = MFMA_K16(pa.s4, vfc[1][kc], oB);
    }
    rs += __shfl_xor(rs, 16);
    rs += __shfl_xor(rs, 32);
    l += rs;
}

__global__ __launch_bounds__(256) void flash(const uint16_t* __restrict__ qb,
                                             const uint16_t* __restrict__ kb,
                                             const uint16_t* __restrict__ vtb,
                                             uint16_t* __restrict__ concat) {
    int tid = threadIdx.x, wv = tid >> 6, lane = tid & 63;
    int c16 = lane & 15, quad = lane >> 4;
    int bh = blockIdx.y;
    int q0 = (blockIdx.x << 7) + wv * 32;
    size_t base = (size_t)bh << 12;
    bf16x8 qf0 = *(const bf16x8*)(qb + (base + q0 + c16) * 32 + quad * 8);
    bf16x8 qf1 = *(const bf16x8*)(qb + (base + q0 + 16 + c16) * 32 + quad * 8);
    f32x4 zero = {0.f, 0.f, 0.f, 0.f};
    f32x4 o00 = zero, o01 = zero, o10 = zero, o11 = zero;
    float l0 = 0.f, l1 = 0.f;
    const uint16_t* kp = kb + (base + c16) * 32 + quad * 8;              // +k*32
    const uint16_t* vp0 = vtb + ((size_t)bh * 32 + c16) * 4096 + quad * 4;  // +k
    const uint16_t* vp1 = vp0 + 16 * 4096;
    bf16x8 kf[2][4];
    short4v vf[2][2][4];
#pragma unroll
    for (int kc = 0; kc < 4; ++kc) {
        kf[0][kc] = *(const bf16x8*)(kp + kc * 16 * 32);
        vf[0][0][kc] = *(const short4v*)(vp0 + kc * 16);
        vf[0][1][kc] = *(const short4v*)(vp1 + kc * 16);
    }
#define FSTEP(CUR, NXT, KT)                                                       \
    {                                                                             \
        int k1 = (((KT) + 1) & 63) * 64;                                          \
        _Pragma("unroll") for (int kc = 0; kc < 4; ++kc) {                        \
            kf[NXT][kc] = *(const bf16x8*)(kp + (k1 + kc * 16) * 32);             \
            vf[NXT][0][kc] = *(const short4v*)(vp0 + k1 + kc * 16);               \
            vf[NXT][1][kc] = *(const short4v*)(vp1 + k1 + kc * 16);               \
        }                                                                         \
        attn_qblock(kf[CUR], vf[CUR], qf0, o00, o01, l0);                         \
        attn_qblock(kf[CUR], vf[CUR], qf1, o10, o11, l1);                         \
    }
    for (int kt2 = 0; kt2 < 32; ++kt2) {
        FSTEP(0, 1, 2 * kt2)
        FSTEP(1, 0, 2 * kt2 + 1)
    }
#undef FSTEP
    int h = bh & 7, bb = bh >> 3;
    float r0 = 1.f / l0, r1 = 1.f / l1;
#pragma unroll
    for (int r = 0; r < 4; ++r) {
        float i0 = __shfl(r0, quad * 4 + r);
        float i1 = __shfl(r1, quad * 4 + r);
        int n = q0 + quad * 4 + r;
        size_t row0 = ((size_t)bb * 4096 + n) * 256 + h * 32;
        size_t row1 = ((size_t)bb * 4096 + n + 16) * 256 + h * 32;
        concat[row0 + c16]      = f2b(o00[r] * i0);
        concat[row0 + 16 + c16] = f2b(o01[r] * i0);
        concat[row1 + c16]      = f2b(o10[r] * i1);
        concat[row1 + 16 + c16] = f2b(o11[r] * i1);
    }
}

// ---------------- kernel 4: output projection, coalesced [b,c,n] stores --
__global__ __launch_bounds__(256) void proj_gemm(const uint16_t* __restrict__ concat,
                                                 const uint16_t* __restrict__ Wo,
                                                 const float* __restrict__ bo,
                                                 float* __restrict__ out) {
    int tid = threadIdx.x, wv = tid >> 6, lane = tid & 63;
    int c16 = lane & 15, quad = lane >> 4;
    int M0 = blockIdx.x * 64 + wv * 16;
    int O0 = blockIdx.y * 64;
    const uint16_t* crow = concat + (size_t)(M0 + c16) * 256;
    f32x4 zero = {0.f, 0.f, 0.f, 0.f};
    f32x4 acc[4] = {zero, zero, zero, zero};
#pragma unroll
    for (int kk = 0; kk < 8; ++kk) {
        int k0 = kk * 32 + quad * 8;
        bf16x8 a = *(const bf16x8*)(crow + k0);
#pragma unroll
        for (int nb = 0; nb < 4; ++nb) {
            bf16x8 b = *(const bf16x8*)(Wo + (size_t)(O0 + nb * 16 + c16) * 256 + k0);
            acc[nb] = MFMA_K32(b, a, acc[nb]);  // D[o][token]
        }
    }
    int bb = M0 >> 12, n = (M0 + c16) & 4095;
#pragma unroll
    for (int nb = 0; nb < 4; ++nb)
#pragma unroll
        for (int r = 0; r < 4; ++r) {
            int o = O0 + nb * 16 + quad * 4 + r;
            out[((size_t)(bb * 256 + o) << 12) + n] = acc[nb][r] + bo[o];
        }
}

extern "C" void kernel_launch(void* const* d_in, const int* in_sizes, int n_in,
                              void* d_out, int out_size, void* d_ws, size_t ws_size,
                              hipStream_t stream) {
    const float* x  = (const float*)d_in[0];
    const float* Wq = (const float*)d_in[1];
    const float* bq = (const float*)d_in[2];
    const float* Wk = (const float*)d_in[3];
    const float* bk = (const float*)d_in[4];
    const float* Wv = (const float*)d_in[5];
    const float* bv = (const float*)d_in[6];
    const float* Wo = (const float*)d_in[7];
    const float* bo = (const float*)d_in[8];
    float* out = (float*)d_out;

    uint16_t* ws   = (uint16_t*)d_ws;
    uint16_t* Wb   = ws;                  // 4*65536 bf16
    uint16_t* tok  = Wb + 4 * 65536;      // [b,N,c]
    uint16_t* q    = tok + 2097152;       // [bh,n,d]
    uint16_t* k    = q + 2097152;         // [bh,n,d]
    uint16_t* vt   = k + 2097152;         // [bh,d,n]
    uint16_t* cc   = vt + 2097152;        // [b,n,c]
    float*    pet  = (float*)(cc + 2097152);  // [256][64]

    wconv_pe<<<1088, 256, 0, stream>>>(Wq, Wk, Wv, Wo, Wb, pet);
    peadd<<<512, 256, 0, stream>>>(x, pet, tok);
    qkv_gemm<<<dim3(128, 4), 256, 0, stream>>>(tok, Wb, bq, bk, bv, q, k, vt);
    flash<<<dim3(32, 16), 256, 0, stream>>>(q, k, vt, cc);
    proj_gemm<<<dim3(128, 4), 256, 0, stream>>>(cc, Wb + 3 * 65536, bo, out);
}

// Round 6
// 177.738 us; speedup vs baseline: 1.4686x; 1.4686x over previous
//
#include <hip/hip_runtime.h>
#include <hip/hip_bf16.h>
#include <cstdint>

typedef float f32x4 __attribute__((ext_vector_type(4)));
typedef __bf16 bf16x8 __attribute__((ext_vector_type(8)));
typedef __bf16 bf16x4 __attribute__((ext_vector_type(4)));
typedef __bf16 bf16x2 __attribute__((ext_vector_type(2)));
typedef short short4v __attribute__((ext_vector_type(4)));
typedef uint32_t uint2v __attribute__((ext_vector_type(2)));

#define MFMA_K32(A, B, C) __builtin_amdgcn_mfma_f32_16x16x32_bf16((A), (B), (C), 0, 0, 0)

// 16x16x16 bf16 MFMA: device resolves one of the first two branches (verified R4);
// the final #else only satisfies the HOST semantic pass and never runs.
#if __has_builtin(__builtin_amdgcn_mfma_f32_16x16x16bf16_1k)
#define MFMA_K16(A, B, C) __builtin_amdgcn_mfma_f32_16x16x16bf16_1k((A), (B), (C), 0, 0, 0)
#elif __has_builtin(__builtin_amdgcn_mfma_f32_16x16x16_bf16)
static __device__ __forceinline__ f32x4 mfma_k16_alt(short4v a, short4v b, f32x4 c) {
    return __builtin_amdgcn_mfma_f32_16x16x16_bf16(*(bf16x4*)&a, *(bf16x4*)&b, c, 0, 0, 0);
}
#define MFMA_K16(A, B, C) mfma_k16_alt((A), (B), (C))
#else
#define MFMA_K16(A, B, C) (C)  // host-pass placeholder only
#endif

#if __has_builtin(__builtin_amdgcn_exp2f)
#define EXP2(x) __builtin_amdgcn_exp2f(x)
#else
#define EXP2(x) exp2f(x)
#endif

// round-to-nearest-even f32 -> bf16 bits
static __device__ __forceinline__ uint16_t f2b(float f) {
    uint32_t u = __float_as_uint(f);
    uint32_t r = (u + 0x7fffu + ((u >> 16) & 1u)) >> 16;
    return (uint16_t)r;
}

// pack two f32 -> bf16x2 dword (low = a, high = b), RNE
static __device__ __forceinline__ uint32_t packbf(float a, float b) {
#if __has_builtin(__builtin_amdgcn_cvt_pk_bf16_f32)
    bf16x2 v = __builtin_amdgcn_cvt_pk_bf16_f32(a, b);
    return *(uint32_t*)&v;
#else
    uint32_t ua = __float_as_uint(a);
    ua += 0x7fffu + ((ua >> 16) & 1u);
    uint32_t ub = __float_as_uint(b);
    ub += 0x7fffu + ((ub >> 16) & 1u);
    return __builtin_amdgcn_perm(ub, ua, 0x07060302);
#endif
}

// ---------------- kernel 0: weights f32->bf16 + PE table -----------------
__global__ __launch_bounds__(256) void wconv_pe(const float* __restrict__ wq,
                                                const float* __restrict__ wk,
                                                const float* __restrict__ wv,
                                                const float* __restrict__ wo,
                                                uint16_t* __restrict__ dst,
                                                float* __restrict__ pet) {
    int bid = blockIdx.x, t = threadIdx.x;
    if (bid < 1024) {
        int idx = bid * 256 + t;
        int which = idx >> 16, off = idx & 65535;
        const float* s = (which == 0) ? wq : (which == 1) ? wk : (which == 2) ? wv : wo;
        dst[idx] = f2b(s[off]);
    } else {
        int idx = (bid - 1024) * 256 + t;   // 0..16383
        int cc = idx >> 6, p = idx & 63;
        int i = (cc & 127) >> 1;
        float dt = __expf((float)(2 * i) * -0.07195578415606394f);  // -(ln 1e4)/128
        float sv, cv;
        __sincosf((float)p * dt, &sv, &cv);
        pet[idx] = (cc & 1) ? cv : sv;
    }
}

// ---------------- kernel 1: tok = (x + pe) transposed, LDS-tiled ----------
__global__ __launch_bounds__(256) void peadd(const float* __restrict__ x,
                                             const float* __restrict__ pet,
                                             uint16_t* __restrict__ tok) {
    __shared__ uint16_t T[64][65];
    int t = threadIdx.x, bid = blockIdx.x;
    int nt = bid & 63, ct = (bid >> 6) & 3, bb = bid >> 8;
    int n0 = nt << 6, c0 = ct << 6;
    int nl = t & 63, cq = t >> 6;
    int n = n0 + nl;
    int posh = n0 >> 6;
#pragma unroll
    for (int p = 0; p < 16; ++p) {
        int cl = cq * 16 + p;
        int cc = c0 + cl;
        float pe = pet[cc * 64 + ((cc & 128) ? posh : nl)];
        T[cl][nl] = f2b(x[((size_t)(bb * 256 + cc) << 12) + n] + pe);
    }
    __syncthreads();
#pragma unroll
    for (int p = 0; p < 16; ++p) {
        int tl = cq * 16 + p;
        tok[(((size_t)(bb << 12) | (n0 + tl)) << 8) + c0 + nl] = T[nl][tl];
    }
}

// ---------------- kernel 2: QKV projection, all mats swapped-operand ------
// grid (128 mtiles, 4 otiles), 256 thr = 4 waves. D[o][n]; Q/K packed 8B stores.
__global__ __launch_bounds__(256) void qkv_gemm(const uint16_t* __restrict__ tok,
                                                const uint16_t* __restrict__ Wall,
                                                const float* __restrict__ bq,
                                                const float* __restrict__ bk,
                                                const float* __restrict__ bv,
                                                uint16_t* __restrict__ qo,
                                                uint16_t* __restrict__ ko,
                                                uint16_t* __restrict__ vo) {
    int tid = threadIdx.x, wv = tid >> 6, lane = tid & 63;
    int c16 = lane & 15, quad = lane >> 4;
    int M0 = blockIdx.x * 64 + wv * 16;
    int O0 = blockIdx.y * 64;
    const uint16_t* arow = tok + (size_t)(M0 + c16) * 256;
    bf16x8 af[8];
#pragma unroll
    for (int kk = 0; kk < 8; ++kk) af[kk] = *(const bf16x8*)(arow + kk * 32 + quad * 8);
    f32x4 zero = {0.f, 0.f, 0.f, 0.f};
    int bb = M0 >> 12, n = (M0 + c16) & 4095;
#pragma unroll
    for (int mat = 0; mat < 3; ++mat) {
        const uint16_t* W = Wall + (size_t)mat * 65536;
        f32x4 acc[4] = {zero, zero, zero, zero};
#pragma unroll
        for (int kk = 0; kk < 8; ++kk) {
            int k0 = kk * 32 + quad * 8;
#pragma unroll
            for (int nb = 0; nb < 4; ++nb)
                acc[nb] = MFMA_K32(*(const bf16x8*)(W + (size_t)(O0 + nb * 16 + c16) * 256 + k0),
                                   af[kk], acc[nb]);  // D[o][n]
        }
        const float* bias = (mat == 0) ? bq : (mat == 1) ? bk : bv;
        if (mat < 2) {
            // q gets 1/sqrt(32)*log2(e) folded in (softmax uses exp2)
            float scale = (mat == 0) ? 0.25505654134660127f : 1.0f;
            uint16_t* dst = (mat == 0) ? qo : ko;
#pragma unroll
            for (int nb = 0; nb < 4; ++nb) {
                int o = O0 + nb * 16 + quad * 4;          // o..o+3, same head
                f32x4 bi = *(const f32x4*)(bias + o);
                int h = o >> 5, dd = o & 31;
                uint2v pk;
                pk[0] = packbf((acc[nb][0] + bi[0]) * scale, (acc[nb][1] + bi[1]) * scale);
                pk[1] = packbf((acc[nb][2] + bi[2]) * scale, (acc[nb][3] + bi[3]) * scale);
                *(uint2v*)(dst + ((size_t)(bb * 8 + h) * 4096 + n) * 32 + dd) = pk;
            }
        } else {
            // V^T [bh,d,n]
#pragma unroll
            for (int nb = 0; nb < 4; ++nb)
#pragma unroll
                for (int r = 0; r < 4; ++r) {
                    int o = O0 + nb * 16 + quad * 4 + r;
                    vo[((size_t)(bb * 8 + (o >> 5)) * 32 + (o & 31)) * 4096 + n] =
                        f2b(acc[nb][r] + bias[o]);
                }
        }
    }
}

// ---------------- kernel 3: flash attention, LDS-staged + in-block k-split
// grid (32 qtiles of 128, 16 bh), block 512 = 8 waves.
// waves 0-3: k in [0,2048); waves 4-7: k in [2048,4096). wave owns 32 q rows.
// K16-PV trick: P never leaves registers; partial (o,l) combined in LDS.
static __device__ __forceinline__ void attn_qblock(const bf16x8 (&kf)[4],
                                                   const short4v (&vf)[2][4],
                                                   bf16x8 qf, f32x4& oA, f32x4& oB,
                                                   float& l) {
    f32x4 zero = {0.f, 0.f, 0.f, 0.f};
    f32x4 s[4];
#pragma unroll
    for (int kc = 0; kc < 4; ++kc) s[kc] = MFMA_K32(kf[kc], qf, zero);
    float rs = 0.f;
#pragma unroll
    for (int kc = 0; kc < 4; ++kc) {
#pragma unroll
        for (int r = 0; r < 4; ++r) {
            s[kc][r] = EXP2(s[kc][r]);
            rs += s[kc][r];
        }
        union { short4v s4; uint32_t u[2]; } pa;
        pa.u[0] = packbf(s[kc][0], s[kc][1]);
        pa.u[1] = packbf(s[kc][2], s[kc][3]);
        oA = MFMA_K16(pa.s4, vf[0][kc], oA);
        oB = MFMA_K16(pa.s4, vf[1][kc], oB);
    }
    rs += __shfl_xor(rs, 16);
    rs += __shfl_xor(rs, 32);
    l += rs;
}

__global__ __launch_bounds__(512, 4) void flash(const uint16_t* __restrict__ qb,
                                                const uint16_t* __restrict__ kb,
                                                const uint16_t* __restrict__ vtb,
                                                uint16_t* __restrict__ concat) {
    // per half: Kt[2][64][40] (10240 B) + Vt[2][32][72] (9216 B) = 19456 B
    __shared__ __align__(16) char smem[38912];
    int tid = threadIdx.x, wv = tid >> 6, lane = tid & 63;
    int c16 = lane & 15, quad = lane >> 4;
    int half = tid >> 8, t2 = tid & 255;
    int bh = blockIdx.y;
    int q0 = (blockIdx.x << 7) + (wv & 3) * 32;
    size_t base = (size_t)bh << 12;

    uint16_t* KT = (uint16_t*)(smem + half * 19456);          // [2][64][40]
    uint16_t* VT = (uint16_t*)(smem + half * 19456 + 10240);  // [2][32][72]

    // staging pointers (each thread: one 16B K slice + one 16B V slice)
    // K is [bh][4096][32]: row index = base + half*2048 + (t2>>2)  (R5 bug: base
    // was outside the *32 -> heads bh>=1 read head-0 K rows; fixed here)
    const uint16_t* kgp = kb + (base + (size_t)half * 2048 + (t2 >> 2)) * 32 + (t2 & 3) * 8;
    const uint16_t* vgp = vtb + ((size_t)bh * 32 + (t2 >> 3)) * 4096 + half * 2048 + (t2 & 7) * 8;
    uint16_t* kls = KT + (t2 >> 2) * 40 + (t2 & 3) * 8;   // + buf*2560
    uint16_t* vls = VT + (t2 >> 3) * 72 + (t2 & 7) * 8;   // + buf*2304

    // Q fragments (B-operand): rows q0+c16 and q0+16+c16
    bf16x8 qf0 = *(const bf16x8*)(qb + (base + q0 + c16) * 32 + quad * 8);
    bf16x8 qf1 = *(const bf16x8*)(qb + (base + q0 + 16 + c16) * 32 + quad * 8);

    f32x4 zero = {0.f, 0.f, 0.f, 0.f};
    f32x4 o00 = zero, o01 = zero, o10 = zero, o11 = zero;
    float l0 = 0.f, l1 = 0.f;

    // prologue: stage tile 0 into buf 0
    {
        bf16x8 kr = *(const bf16x8*)kgp;
        bf16x8 vr = *(const bf16x8*)vgp;
        *(bf16x8*)kls = kr;
        *(bf16x8*)vls = vr;
    }
    __syncthreads();

    for (int kt = 0; kt < 32; ++kt) {
        int cur = kt & 1;
        int kn = (kt + 1) & 31;  // last iter re-loads tile 0 (in-bounds, unused)
        bf16x8 kr = *(const bf16x8*)(kgp + (size_t)kn * 2048);
        bf16x8 vr = *(const bf16x8*)(vgp + kn * 64);
        const uint16_t* kfp = KT + cur * 2560 + c16 * 40 + quad * 8;
        const uint16_t* vfp = VT + cur * 2304 + c16 * 72 + quad * 4;
        bf16x8 kf[4];
        short4v vf[2][4];
#pragma unroll
        for (int kc = 0; kc < 4; ++kc) kf[kc] = *(const bf16x8*)(kfp + kc * 640);
#pragma unroll
        for (int kc = 0; kc < 4; ++kc) {
            vf[0][kc] = *(const short4v*)(vfp + kc * 16);
            vf[1][kc] = *(const short4v*)(vfp + 1152 + kc * 16);
        }
        attn_qblock(kf, vf, qf0, o00, o01, l0);
        attn_qblock(kf, vf, qf1, o10, o11, l1);
        *(bf16x8*)(kls + (cur ^ 1) * 2560) = kr;
        *(bf16x8*)(vls + (cur ^ 1) * 2304) = vr;
        __syncthreads();
    }

    // combine the two k-halves via LDS (staging area is dead now)
    float* ov = (float*)smem;            // [4][64][17] = 17408 B
    float* lv = (float*)(smem + 17408);  // [4][64][2]  =  2048 B
    if (wv >= 4) {
        float* d = ov + ((wv - 4) * 64 + lane) * 17;
#pragma unroll
        for (int r = 0; r < 4; ++r) {
            d[r] = o00[r]; d[4 + r] = o01[r]; d[8 + r] = o10[r]; d[12 + r] = o11[r];
        }
        float* dl = lv + ((wv - 4) * 64 + lane) * 2;
        dl[0] = l0; dl[1] = l1;
    }
    __syncthreads();
    if (wv < 4) {
        const float* s = ov + (wv * 64 + lane) * 17;
#pragma unroll
        for (int r = 0; r < 4; ++r) {
            o00[r] += s[r]; o01[r] += s[4 + r]; o10[r] += s[8 + r]; o11[r] += s[12 + r];
        }
        const float* sl = lv + (wv * 64 + lane) * 2;
        l0 += sl[0]; l1 += sl[1];
        int h = bh & 7, bb = bh >> 3;
        float r0 = 1.f / l0, r1 = 1.f / l1;
#pragma unroll
        for (int r = 0; r < 4; ++r) {
            float i0 = __shfl(r0, quad * 4 + r);
            float i1 = __shfl(r1, quad * 4 + r);
            int n = q0 + quad * 4 + r;
            size_t row0 = ((size_t)bb * 4096 + n) * 256 + h * 32;
            size_t row1 = ((size_t)bb * 4096 + n + 16) * 256 + h * 32;
            concat[row0 + c16]      = f2b(o00[r] * i0);
            concat[row0 + 16 + c16] = f2b(o01[r] * i0);
            concat[row1 + c16]      = f2b(o10[r] * i1);
            concat[row1 + 16 + c16] = f2b(o11[r] * i1);
        }
    }
}

// ---------------- kernel 4: output projection, coalesced [b,c,n] stores --
__global__ __launch_bounds__(256) void proj_gemm(const uint16_t* __restrict__ concat,
                                                 const uint16_t* __restrict__ Wo,
                                                 const float* __restrict__ bo,
                                                 float* __restrict__ out) {
    int tid = threadIdx.x, wv = tid >> 6, lane = tid & 63;
    int c16 = lane & 15, quad = lane >> 4;
    int M0 = blockIdx.x * 64 + wv * 16;
    int O0 = blockIdx.y * 64;
    const uint16_t* crow = concat + (size_t)(M0 + c16) * 256;
    f32x4 zero = {0.f, 0.f, 0.f, 0.f};
    f32x4 acc[4] = {zero, zero, zero, zero};
#pragma unroll
    for (int kk = 0; kk < 8; ++kk) {
        int k0 = kk * 32 + quad * 8;
        bf16x8 a = *(const bf16x8*)(crow + k0);
#pragma unroll
        for (int nb = 0; nb < 4; ++nb) {
            bf16x8 b = *(const bf16x8*)(Wo + (size_t)(O0 + nb * 16 + c16) * 256 + k0);
            acc[nb] = MFMA_K32(b, a, acc[nb]);  // D[o][token]
        }
    }
    int bb = M0 >> 12, n = (M0 + c16) & 4095;
#pragma unroll
    for (int nb = 0; nb < 4; ++nb)
#pragma unroll
        for (int r = 0; r < 4; ++r) {
            int o = O0 + nb * 16 + quad * 4 + r;
            out[((size_t)(bb * 256 + o) << 12) + n] = acc[nb][r] + bo[o];
        }
}

extern "C" void kernel_launch(void* const* d_in, const int* in_sizes, int n_in,
                              void* d_out, int out_size, void* d_ws, size_t ws_size,
                              hipStream_t stream) {
    const float* x  = (const float*)d_in[0];
    const float* Wq = (const float*)d_in[1];
    const float* bq = (const float*)d_in[2];
    const float* Wk = (const float*)d_in[3];
    const float* bk = (const float*)d_in[4];
    const float* Wv = (const float*)d_in[5];
    const float* bv = (const float*)d_in[6];
    const float* Wo = (const float*)d_in[7];
    const float* bo = (const float*)d_in[8];
    float* out = (float*)d_out;

    uint16_t* ws   = (uint16_t*)d_ws;
    uint16_t* Wb   = ws;                  // 4*65536 bf16
    uint16_t* tok  = Wb + 4 * 65536;      // [b,N,c]
    uint16_t* q    = tok + 2097152;       // [bh,n,d]
    uint16_t* k    = q + 2097152;         // [bh,n,d]
    uint16_t* vt   = k + 2097152;         // [bh,d,n]
    uint16_t* cc   = vt + 2097152;        // [b,n,c]
    float*    pet  = (float*)(cc + 2097152);  // [256][64]

    wconv_pe<<<1088, 256, 0, stream>>>(Wq, Wk, Wv, Wo, Wb, pet);
    peadd<<<512, 256, 0, stream>>>(x, pet, tok);
    qkv_gemm<<<dim3(128, 4), 256, 0, stream>>>(tok, Wb, bq, bk, bv, q, k, vt);
    flash<<<dim3(32, 16), 512, 0, stream>>>(q, k, vt, cc);
    proj_gemm<<<dim3(128, 4), 256, 0, stream>>>(cc, Wb + 3 * 65536, bo, out);
}

// Round 7
// 149.612 us; speedup vs baseline: 1.7447x; 1.1880x over previous
//
#include <hip/hip_runtime.h>
#include <hip/hip_bf16.h>
#include <cstdint>

typedef float f32x4 __attribute__((ext_vector_type(4)));
typedef __bf16 bf16x8 __attribute__((ext_vector_type(8)));
typedef __bf16 bf16x4 __attribute__((ext_vector_type(4)));
typedef __bf16 bf16x2 __attribute__((ext_vector_type(2)));
typedef short short4v __attribute__((ext_vector_type(4)));
typedef uint32_t uint2v __attribute__((ext_vector_type(2)));

#define MFMA_K32(A, B, C) __builtin_amdgcn_mfma_f32_16x16x32_bf16((A), (B), (C), 0, 0, 0)

// 16x16x16 bf16 MFMA: device resolves one of the first two branches (verified R4/R6);
// the final #else only satisfies the HOST semantic pass and never runs.
#if __has_builtin(__builtin_amdgcn_mfma_f32_16x16x16bf16_1k)
#define MFMA_K16(A, B, C) __builtin_amdgcn_mfma_f32_16x16x16bf16_1k((A), (B), (C), 0, 0, 0)
#elif __has_builtin(__builtin_amdgcn_mfma_f32_16x16x16_bf16)
static __device__ __forceinline__ f32x4 mfma_k16_alt(short4v a, short4v b, f32x4 c) {
    return __builtin_amdgcn_mfma_f32_16x16x16_bf16(*(bf16x4*)&a, *(bf16x4*)&b, c, 0, 0, 0);
}
#define MFMA_K16(A, B, C) mfma_k16_alt((A), (B), (C))
#else
#define MFMA_K16(A, B, C) (C)  // host-pass placeholder only
#endif

#if __has_builtin(__builtin_amdgcn_exp2f)
#define EXP2(x) __builtin_amdgcn_exp2f(x)
#else
#define EXP2(x) exp2f(x)
#endif

// round-to-nearest-even f32 -> bf16 bits
static __device__ __forceinline__ uint16_t f2b(float f) {
    uint32_t u = __float_as_uint(f);
    uint32_t r = (u + 0x7fffu + ((u >> 16) & 1u)) >> 16;
    return (uint16_t)r;
}

// pack two f32 -> bf16x2 dword (low = a, high = b), RNE
static __device__ __forceinline__ uint32_t packbf(float a, float b) {
#if __has_builtin(__builtin_amdgcn_cvt_pk_bf16_f32)
    bf16x2 v = __builtin_amdgcn_cvt_pk_bf16_f32(a, b);
    return *(uint32_t*)&v;
#else
    uint32_t ua = __float_as_uint(a);
    ua += 0x7fffu + ((ua >> 16) & 1u);
    uint32_t ub = __float_as_uint(b);
    ub += 0x7fffu + ((ub >> 16) & 1u);
    return __builtin_amdgcn_perm(ub, ua, 0x07060302);
#endif
}

// ---------------- kernel 0: weights f32->bf16 + PE table -----------------
__global__ __launch_bounds__(256) void wconv_pe(const float* __restrict__ wq,
                                                const float* __restrict__ wk,
                                                const float* __restrict__ wv,
                                                const float* __restrict__ wo,
                                                uint16_t* __restrict__ dst,
                                                float* __restrict__ pet) {
    int bid = blockIdx.x, t = threadIdx.x;
    if (bid < 1024) {
        int idx = bid * 256 + t;
        int which = idx >> 16, off = idx & 65535;
        const float* s = (which == 0) ? wq : (which == 1) ? wk : (which == 2) ? wv : wo;
        dst[idx] = f2b(s[off]);
    } else {
        int idx = (bid - 1024) * 256 + t;   // 0..16383
        int cc = idx >> 6, p = idx & 63;
        int i = (cc & 127) >> 1;
        float dt = __expf((float)(2 * i) * -0.07195578415606394f);  // -(ln 1e4)/128
        float sv, cv;
        __sincosf((float)p * dt, &sv, &cv);
        pet[idx] = (cc & 1) ? cv : sv;
    }
}

// ---------------- kernel 1: tok = (x + pe) transposed, LDS-tiled ----------
__global__ __launch_bounds__(256) void peadd(const float* __restrict__ x,
                                             const float* __restrict__ pet,
                                             uint16_t* __restrict__ tok) {
    __shared__ uint16_t T[64][65];
    int t = threadIdx.x, bid = blockIdx.x;
    int nt = bid & 63, ct = (bid >> 6) & 3, bb = bid >> 8;
    int n0 = nt << 6, c0 = ct << 6;
    int nl = t & 63, cq = t >> 6;
    int n = n0 + nl;
    int posh = n0 >> 6;
#pragma unroll
    for (int p = 0; p < 16; ++p) {
        int cl = cq * 16 + p;
        int cc = c0 + cl;
        float pe = pet[cc * 64 + ((cc & 128) ? posh : nl)];
        T[cl][nl] = f2b(x[((size_t)(bb * 256 + cc) << 12) + n] + pe);
    }
    __syncthreads();
#pragma unroll
    for (int p = 0; p < 16; ++p) {
        int tl = cq * 16 + p;
        tok[(((size_t)(bb << 12) | (n0 + tl)) << 8) + c0 + nl] = T[nl][tl];
    }
}

// ---------------- kernel 2: QKV projection, W LDS-staged ------------------
// grid (128 mtiles, 4 otiles), 256 thr = 4 waves. D[o][n].
__global__ __launch_bounds__(256) void qkv_gemm(const uint16_t* __restrict__ tok,
                                                const uint16_t* __restrict__ Wall,
                                                const float* __restrict__ bq,
                                                const float* __restrict__ bk,
                                                const float* __restrict__ bv,
                                                uint16_t* __restrict__ qo,
                                                uint16_t* __restrict__ ko,
                                                uint16_t* __restrict__ vo) {
    __shared__ __align__(16) uint16_t WS[64][264];
    int tid = threadIdx.x, wv = tid >> 6, lane = tid & 63;
    int c16 = lane & 15, quad = lane >> 4;
    int M0 = blockIdx.x * 64 + wv * 16;
    int O0 = blockIdx.y * 64;
    const uint16_t* arow = tok + (size_t)(M0 + c16) * 256;
    bf16x8 af[8];
#pragma unroll
    for (int kk = 0; kk < 8; ++kk) af[kk] = *(const bf16x8*)(arow + kk * 32 + quad * 8);
    f32x4 zero = {0.f, 0.f, 0.f, 0.f};
    int bb = M0 >> 12, n = (M0 + c16) & 4095;
    int srow = tid >> 5, sch = (tid & 31) << 3;  // staging: 2048 elems/pass
    for (int mat = 0; mat < 3; ++mat) {
        const uint16_t* Wg = Wall + (size_t)mat * 65536 + (size_t)O0 * 256;
        __syncthreads();  // previous WS readers done
#pragma unroll
        for (int p = 0; p < 8; ++p)
            *(bf16x8*)(&WS[p * 8 + srow][sch]) = *(const bf16x8*)(Wg + (p * 8 + srow) * 256 + sch);
        __syncthreads();
        f32x4 acc[4] = {zero, zero, zero, zero};
#pragma unroll
        for (int kk = 0; kk < 8; ++kk) {
            int k0 = kk * 32 + quad * 8;
#pragma unroll
            for (int nb = 0; nb < 4; ++nb)
                acc[nb] = MFMA_K32(*(const bf16x8*)(&WS[nb * 16 + c16][k0]),
                                   af[kk], acc[nb]);  // D[o][n]
        }
        const float* bias = (mat == 0) ? bq : (mat == 1) ? bk : bv;
        if (mat < 2) {
            // q gets 1/sqrt(32)*log2(e) folded in (softmax uses exp2)
            float scale = (mat == 0) ? 0.25505654134660127f : 1.0f;
            uint16_t* dst = (mat == 0) ? qo : ko;
#pragma unroll
            for (int nb = 0; nb < 4; ++nb) {
                int o = O0 + nb * 16 + quad * 4;          // o..o+3, same head
                f32x4 bi = *(const f32x4*)(bias + o);
                int h = o >> 5, dd = o & 31;
                uint2v pk;
                pk[0] = packbf((acc[nb][0] + bi[0]) * scale, (acc[nb][1] + bi[1]) * scale);
                pk[1] = packbf((acc[nb][2] + bi[2]) * scale, (acc[nb][3] + bi[3]) * scale);
                *(uint2v*)(dst + ((size_t)(bb * 8 + h) * 4096 + n) * 32 + dd) = pk;
            }
        } else {
            // V^T [bh,d,n]
#pragma unroll
            for (int nb = 0; nb < 4; ++nb)
#pragma unroll
                for (int r = 0; r < 4; ++r) {
                    int o = O0 + nb * 16 + quad * 4 + r;
                    vo[((size_t)(bb * 8 + (o >> 5)) * 32 + (o & 31)) * 4096 + n] =
                        f2b(acc[nb][r] + bias[o]);
                }
        }
    }
}

// ---------------- kernel 3: flash attention, LDS-staged + in-block k-split
// grid (32 qtiles of 128, 16 bh), block 512 = 8 waves; wave owns 32 q rows.
// K16-PV trick: P never leaves registers. Row-sum l via ones-frag MFMA (oS):
// D[q][*] = rowsum(P), row-aligned with oA/oB -> no VALU adds, no shuffles.
static __device__ __forceinline__ void attn_qblock(const bf16x8 (&kf)[4],
                                                   const short4v (&vf)[2][4],
                                                   bf16x8 qf, f32x4& oA, f32x4& oB,
                                                   f32x4& oS) {
    f32x4 zero = {0.f, 0.f, 0.f, 0.f};
    const short4v ones = {0x3F80, 0x3F80, 0x3F80, 0x3F80};  // bf16 1.0 x4
    f32x4 s[4];
#pragma unroll
    for (int kc = 0; kc < 4; ++kc) s[kc] = MFMA_K32(kf[kc], qf, zero);
#pragma unroll
    for (int kc = 0; kc < 4; ++kc) {
#pragma unroll
        for (int r = 0; r < 4; ++r) s[kc][r] = EXP2(s[kc][r]);
        union { short4v s4; uint32_t u[2]; } pa;
        pa.u[0] = packbf(s[kc][0], s[kc][1]);
        pa.u[1] = packbf(s[kc][2], s[kc][3]);
        oA = MFMA_K16(pa.s4, vf[0][kc], oA);
        oB = MFMA_K16(pa.s4, vf[1][kc], oB);
        oS = MFMA_K16(pa.s4, ones, oS);
    }
}

__global__ __launch_bounds__(512, 4) void flash(const uint16_t* __restrict__ qb,
                                                const uint16_t* __restrict__ kb,
                                                const uint16_t* __restrict__ vtb,
                                                uint16_t* __restrict__ concat) {
    // per half: Kt[2][64][40] (10240 B) + Vt[2][32][72] (9216 B) = 19456 B
    __shared__ __align__(16) char smem[38912];
    int tid = threadIdx.x, wv = tid >> 6, lane = tid & 63;
    int c16 = lane & 15, quad = lane >> 4;
    int half = tid >> 8, t2 = tid & 255;
    int bh = blockIdx.y;
    int q0 = (blockIdx.x << 7) + (wv & 3) * 32;
    size_t base = (size_t)bh << 12;

    uint16_t* KT = (uint16_t*)(smem + half * 19456);          // [2][64][40]
    uint16_t* VT = (uint16_t*)(smem + half * 19456 + 10240);  // [2][32][72]

    // staging: K is [bh][4096][32]; row = base + half*2048 + (t2>>2)
    const uint16_t* kgp = kb + (base + (size_t)half * 2048 + (t2 >> 2)) * 32 + (t2 & 3) * 8;
    const uint16_t* vgp = vtb + ((size_t)bh * 32 + (t2 >> 3)) * 4096 + half * 2048 + (t2 & 7) * 8;
    uint16_t* kls = KT + (t2 >> 2) * 40 + (t2 & 3) * 8;   // + buf*2560
    uint16_t* vls = VT + (t2 >> 3) * 72 + (t2 & 7) * 8;   // + buf*2304

    // Q fragments (B-operand): rows q0+c16 and q0+16+c16
    bf16x8 qf0 = *(const bf16x8*)(qb + (base + q0 + c16) * 32 + quad * 8);
    bf16x8 qf1 = *(const bf16x8*)(qb + (base + q0 + 16 + c16) * 32 + quad * 8);

    f32x4 zero = {0.f, 0.f, 0.f, 0.f};
    f32x4 o00 = zero, o01 = zero, o10 = zero, o11 = zero;
    f32x4 oS0 = zero, oS1 = zero;

    // prologue: stage tile 0 into buf 0
    {
        bf16x8 kr = *(const bf16x8*)kgp;
        bf16x8 vr = *(const bf16x8*)vgp;
        *(bf16x8*)kls = kr;
        *(bf16x8*)vls = vr;
    }
    __syncthreads();

    for (int kt = 0; kt < 32; ++kt) {
        int cur = kt & 1;
        int kn = (kt + 1) & 31;  // last iter re-loads tile 0 (in-bounds, unused)
        bf16x8 kr = *(const bf16x8*)(kgp + (size_t)kn * 2048);
        bf16x8 vr = *(const bf16x8*)(vgp + kn * 64);
        const uint16_t* kfp = KT + cur * 2560 + c16 * 40 + quad * 8;
        const uint16_t* vfp = VT + cur * 2304 + c16 * 72 + quad * 4;
        bf16x8 kf[4];
        short4v vf[2][4];
#pragma unroll
        for (int kc = 0; kc < 4; ++kc) kf[kc] = *(const bf16x8*)(kfp + kc * 640);
#pragma unroll
        for (int kc = 0; kc < 4; ++kc) {
            vf[0][kc] = *(const short4v*)(vfp + kc * 16);
            vf[1][kc] = *(const short4v*)(vfp + 1152 + kc * 16);
        }
        attn_qblock(kf, vf, qf0, o00, o01, oS0);
        attn_qblock(kf, vf, qf1, o10, o11, oS1);
        *(bf16x8*)(kls + (cur ^ 1) * 2560) = kr;
        *(bf16x8*)(vls + (cur ^ 1) * 2304) = vr;
        __syncthreads();
    }

    // combine the two k-halves via LDS (staging area is dead now)
    float* ov = (float*)smem;  // [4][64][25] = 25600 B
    if (wv >= 4) {
        float* d = ov + ((wv - 4) * 64 + lane) * 25;
#pragma unroll
        for (int r = 0; r < 4; ++r) {
            d[r] = o00[r]; d[4 + r] = o01[r]; d[8 + r] = o10[r]; d[12 + r] = o11[r];
            d[16 + r] = oS0[r]; d[20 + r] = oS1[r];
        }
    }
    __syncthreads();
    if (wv < 4) {
        const float* s = ov + (wv * 64 + lane) * 25;
#pragma unroll
        for (int r = 0; r < 4; ++r) {
            o00[r] += s[r]; o01[r] += s[4 + r]; o10[r] += s[8 + r]; o11[r] += s[12 + r];
            oS0[r] += s[16 + r]; oS1[r] += s[20 + r];
        }
        int h = bh & 7, bb = bh >> 3;
#pragma unroll
        for (int r = 0; r < 4; ++r) {
            float i0 = 1.f / oS0[r];   // l row-aligned with o rows: no shuffle
            float i1 = 1.f / oS1[r];
            int n = q0 + quad * 4 + r;
            size_t row0 = ((size_t)bb * 4096 + n) * 256 + h * 32;
            size_t row1 = ((size_t)bb * 4096 + n + 16) * 256 + h * 32;
            concat[row0 + c16]      = f2b(o00[r] * i0);
            concat[row0 + 16 + c16] = f2b(o01[r] * i0);
            concat[row1 + c16]      = f2b(o10[r] * i1);
            concat[row1 + 16 + c16] = f2b(o11[r] * i1);
        }
    }
}

// ---------------- kernel 4: output projection, W LDS-staged --------------
__global__ __launch_bounds__(256) void proj_gemm(const uint16_t* __restrict__ concat,
                                                 const uint16_t* __restrict__ Wo,
                                                 const float* __restrict__ bo,
                                                 float* __restrict__ out) {
    __shared__ __align__(16) uint16_t WS[64][264];
    int tid = threadIdx.x, wv = tid >> 6, lane = tid & 63;
    int c16 = lane & 15, quad = lane >> 4;
    int M0 = blockIdx.x * 64 + wv * 16;
    int O0 = blockIdx.y * 64;
    int srow = tid >> 5, sch = (tid & 31) << 3;
    const uint16_t* Wg = Wo + (size_t)O0 * 256;
#pragma unroll
    for (int p = 0; p < 8; ++p)
        *(bf16x8*)(&WS[p * 8 + srow][sch]) = *(const bf16x8*)(Wg + (p * 8 + srow) * 256 + sch);
    const uint16_t* crow = concat + (size_t)(M0 + c16) * 256;
    bf16x8 af[8];
#pragma unroll
    for (int kk = 0; kk < 8; ++kk) af[kk] = *(const bf16x8*)(crow + kk * 32 + quad * 8);
    __syncthreads();
    f32x4 zero = {0.f, 0.f, 0.f, 0.f};
    f32x4 acc[4] = {zero, zero, zero, zero};
#pragma unroll
    for (int kk = 0; kk < 8; ++kk) {
        int k0 = kk * 32 + quad * 8;
#pragma unroll
        for (int nb = 0; nb < 4; ++nb)
            acc[nb] = MFMA_K32(*(const bf16x8*)(&WS[nb * 16 + c16][k0]),
                               af[kk], acc[nb]);  // D[o][token]
    }
    int bb = M0 >> 12, n = (M0 + c16) & 4095;
#pragma unroll
    for (int nb = 0; nb < 4; ++nb)
#pragma unroll
        for (int r = 0; r < 4; ++r) {
            int o = O0 + nb * 16 + quad * 4 + r;
            out[((size_t)(bb * 256 + o) << 12) + n] = acc[nb][r] + bo[o];
        }
}

extern "C" void kernel_launch(void* const* d_in, const int* in_sizes, int n_in,
                              void* d_out, int out_size, void* d_ws, size_t ws_size,
                              hipStream_t stream) {
    const float* x  = (const float*)d_in[0];
    const float* Wq = (const float*)d_in[1];
    const float* bq = (const float*)d_in[2];
    const float* Wk = (const float*)d_in[3];
    const float* bk = (const float*)d_in[4];
    const float* Wv = (const float*)d_in[5];
    const float* bv = (const float*)d_in[6];
    const float* Wo = (const float*)d_in[7];
    const float* bo = (const float*)d_in[8];
    float* out = (float*)d_out;

    uint16_t* ws   = (uint16_t*)d_ws;
    uint16_t* Wb   = ws;                  // 4*65536 bf16
    uint16_t* tok  = Wb + 4 * 65536;      // [b,N,c]
    uint16_t* q    = tok + 2097152;       // [bh,n,d]
    uint16_t* k    = q + 2097152;         // [bh,n,d]
    uint16_t* vt   = k + 2097152;         // [bh,d,n]
    uint16_t* cc   = vt + 2097152;        // [b,n,c]
    float*    pet  = (float*)(cc + 2097152);  // [256][64]

    wconv_pe<<<1088, 256, 0, stream>>>(Wq, Wk, Wv, Wo, Wb, pet);
    peadd<<<512, 256, 0, stream>>>(x, pet, tok);
    qkv_gemm<<<dim3(128, 4), 256, 0, stream>>>(tok, Wb, bq, bk, bv, q, k, vt);
    flash<<<dim3(32, 16), 512, 0, stream>>>(q, k, vt, cc);
    proj_gemm<<<dim3(128, 4), 256, 0, stream>>>(cc, Wb + 3 * 65536, bo, out);
}